// Round 1
// baseline (212.446 us; speedup 1.0000x reference)
//
#include <hip/hip_runtime.h>

typedef short bf16x8 __attribute__((ext_vector_type(8)));
typedef unsigned short u16x8 __attribute__((ext_vector_type(8)));
typedef float f32x4 __attribute__((ext_vector_type(4)));

__device__ __forceinline__ float bf2f(unsigned short u) {
  union { unsigned int i; float f; } v; v.i = ((unsigned int)u) << 16; return v.f;
}
__device__ __forceinline__ unsigned short f2bf(float f) {
  union { float fl; unsigned int i; } v; v.fl = f;
  unsigned int r = v.i + 0x7FFFu + ((v.i >> 16) & 1u);
  return (unsigned short)(r >> 16);
}
__device__ __forceinline__ void gload_lds16(const void* g, void* l) {
  __builtin_amdgcn_global_load_lds(
      (const __attribute__((address_space(1))) void*)g,
      (__attribute__((address_space(3))) void*)l, 16, 0, 0);
}

// ---------------- fp32 -> bf16 conversion (8 elems/thread) ----------------
__global__ __launch_bounds__(256) void cvt_bf16(const float* __restrict__ in,
                                                unsigned short* __restrict__ out, int n8) {
  int i = blockIdx.x * 256 + threadIdx.x;
  if (i >= n8) return;
  float4 a = ((const float4*)in)[2 * i];
  float4 b = ((const float4*)in)[2 * i + 1];
  u16x8 o;
  o[0] = f2bf(a.x); o[1] = f2bf(a.y); o[2] = f2bf(a.z); o[3] = f2bf(a.w);
  o[4] = f2bf(b.x); o[5] = f2bf(b.y); o[6] = f2bf(b.z); o[7] = f2bf(b.w);
  ((u16x8*)out)[i] = o;
}

// ---------------- GEMM NT: out[m][n] = sum_k A[m][k]*B[n][k] ----------------
// 128x128 tile, BK=64, 4 waves (2x2), 4x4 16x16x32 frags/wave, swizzled LDS,
// global_load_lds width-16 staging (m97 structure + T2 swizzle).
template <bool F32OUT>
__global__ __launch_bounds__(256) void gemm_nt(const unsigned short* __restrict__ A,
                                               const unsigned short* __restrict__ B,
                                               void* __restrict__ Cout,
                                               const float* __restrict__ bias,
                                               int M, int N, int K) {
  __shared__ __align__(16) unsigned short a_lds[128 * 64];
  __shared__ __align__(16) unsigned short b_lds[128 * 64];
  const int t = threadIdx.x;
  const int lane = t & 63, w = t >> 6;
  const int wm = w >> 1, wn = w & 1;
  const int r16 = lane >> 4, c16 = lane & 15;
  const int m0 = blockIdx.y * 128, n0 = blockIdx.x * 128;
  f32x4 acc[4][4] = {};
  for (int k0 = 0; k0 < K; k0 += 64) {
#pragma unroll
    for (int i = 0; i < 4; ++i) {
      int s = i * 256 + t;
      int row = s >> 3, c = s & 7;
      int cs = c ^ (row & 7);  // pre-swizzled global source, linear LDS dest
      gload_lds16(A + (size_t)(m0 + row) * K + k0 + cs * 8, (char*)a_lds + s * 16);
      gload_lds16(B + (size_t)(n0 + row) * K + k0 + cs * 8, (char*)b_lds + s * 16);
    }
    __syncthreads();
#pragma unroll
    for (int ks = 0; ks < 2; ++ks) {
      bf16x8 af[4], bfr[4];
#pragma unroll
      for (int mi = 0; mi < 4; ++mi) {
        int row = wm * 64 + mi * 16 + c16;
        int ch = (r16 + ks * 4) ^ (row & 7);
        af[mi] = *(const bf16x8*)&a_lds[row * 64 + ch * 8];
      }
#pragma unroll
      for (int ni = 0; ni < 4; ++ni) {
        int row = wn * 64 + ni * 16 + c16;
        int ch = (r16 + ks * 4) ^ (row & 7);
        bfr[ni] = *(const bf16x8*)&b_lds[row * 64 + ch * 8];
      }
#pragma unroll
      for (int mi = 0; mi < 4; ++mi)
#pragma unroll
        for (int ni = 0; ni < 4; ++ni)
          acc[mi][ni] = __builtin_amdgcn_mfma_f32_16x16x32_bf16(af[mi], bfr[ni], acc[mi][ni], 0, 0, 0);
    }
    __syncthreads();
  }
#pragma unroll
  for (int mi = 0; mi < 4; ++mi)
#pragma unroll
    for (int ni = 0; ni < 4; ++ni)
#pragma unroll
      for (int r = 0; r < 4; ++r) {
        int m = m0 + wm * 64 + mi * 16 + r16 * 4 + r;
        int n = n0 + wn * 64 + ni * 16 + c16;
        float v = acc[mi][ni][r];
        if constexpr (F32OUT) {
          ((float*)Cout)[(size_t)m * N + n] = v + bias[n];
        } else {
          ((unsigned short*)Cout)[(size_t)m * N + n] = f2bf(v);
        }
      }
}

// ---------------- normalize + bias + pack q,k,(v transposed) ----------------
// grid: x = b*32+ltile (64 l's), y = qkv*16+h. 256 thr: li=t>>2 (row), dq=t&3.
__global__ __launch_bounds__(256) void norm_pack(const unsigned short* __restrict__ pre,
                                                 const float* __restrict__ q_bias,
                                                 const float* __restrict__ v_bias,
                                                 const float* __restrict__ scale_mul,
                                                 unsigned short* __restrict__ qo,
                                                 unsigned short* __restrict__ ko,
                                                 unsigned short* __restrict__ vto) {
  __shared__ float tl[64][65];
  const int t = threadIdx.x;
  const int li = t >> 2, dq = t & 3;
  const int tile = blockIdx.x;  // b*32 + lt
  const int sl = blockIdx.y;    // qkv*16 + h
  const int qkv = sl >> 4, h = sl & 15;
  const int b = tile >> 5, lt = tile & 31;
  const int l = lt * 64 + li;
  const int dbase = dq * 16;
  const unsigned short* src = pre + ((size_t)b * 2048 + l) * 3072 + qkv * 1024 + h * 64 + dbase;
  float v[16];
  bf16x8 x0 = *(const bf16x8*)src;
  bf16x8 x1 = *(const bf16x8*)(src + 8);
#pragma unroll
  for (int j = 0; j < 8; ++j) {
    v[j] = bf2f((unsigned short)x0[j]);
    v[8 + j] = bf2f((unsigned short)x1[j]);
  }
  if (qkv == 0) {
#pragma unroll
    for (int j = 0; j < 16; ++j) v[j] += q_bias[h * 64 + dbase + j];
  } else if (qkv == 2) {
#pragma unroll
    for (int j = 0; j < 16; ++j) v[j] += v_bias[h * 64 + dbase + j];
  }
  if (qkv < 2) {
    float ss = 0.f;
#pragma unroll
    for (int j = 0; j < 16; ++j) ss += v[j] * v[j];
    ss += __shfl_xor(ss, 1);
    ss += __shfl_xor(ss, 2);
    float inv = 1.0f / fmaxf(sqrtf(ss), 1e-12f);
    if (qkv == 0) inv *= __expf(fminf(scale_mul[h], 4.6051701859880914f));
    u16x8 o0, o1;
#pragma unroll
    for (int j = 0; j < 8; ++j) {
      o0[j] = f2bf(v[j] * inv);
      o1[j] = f2bf(v[8 + j] * inv);
    }
    unsigned short* dst = (qkv == 0 ? qo : ko) + ((size_t)(b * 16 + h) * 2048 + l) * 64 + dbase;
    *(u16x8*)dst = o0;
    *(u16x8*)(dst + 8) = o1;
  } else {
    // v: transpose via LDS, write (B,H,D,L)
#pragma unroll
    for (int j = 0; j < 16; ++j) tl[li][dbase + j] = v[j];
    __syncthreads();
    const int d = li;
    const int lb = dq * 16;
    u16x8 o0, o1;
#pragma unroll
    for (int j = 0; j < 8; ++j) {
      o0[j] = f2bf(tl[lb + j][d]);
      o1[j] = f2bf(tl[lb + 8 + j][d]);
    }
    unsigned short* dst = vto + ((size_t)(b * 16 + h) * 64 + d) * 2048 + lt * 64 + lb;
    *(u16x8*)dst = o0;
    *(u16x8*)(dst + 8) = o1;
  }
}

// ---------------- flash attention: 64 q-rows/block, 4 waves x 16 rows ----------------
__global__ __launch_bounds__(256) void attn_fwd(const unsigned short* __restrict__ qb,
                                                const unsigned short* __restrict__ kbuf,
                                                const unsigned short* __restrict__ vtb,
                                                const unsigned short* __restrict__ biasb,
                                                unsigned short* __restrict__ oup) {
  __shared__ __align__(16) unsigned short k_lds[64 * 64];
  __shared__ __align__(16) unsigned short vt_lds[64 * 64];
  __shared__ __align__(16) unsigned short p_lds[64 * 64];
  const int t = threadIdx.x;
  const int lane = t & 63, w = t >> 6;
  const int r16 = lane >> 4, c16 = lane & 15;
  const int q0 = blockIdx.x * 64;
  const int bh = blockIdx.y;
  const size_t qk_base = (size_t)bh * 2048 * 64;  // also vt base (same extent)
  bf16x8 aq0, aq1;  // Q fragments held in registers across the whole K loop
  {
    int row = q0 + w * 16 + c16;
    const unsigned short* qp = qb + qk_base + (size_t)row * 64 + r16 * 8;
    aq0 = *(const bf16x8*)qp;
    aq1 = *(const bf16x8*)(qp + 32);
  }
  f32x4 o[4] = {};
  float mrow[4] = {-3e38f, -3e38f, -3e38f, -3e38f};
  float lrow[4] = {0.f, 0.f, 0.f, 0.f};
  const int qrow_g = q0 + w * 16 + r16 * 4;
  for (int kb0 = 0; kb0 < 2048; kb0 += 64) {
#pragma unroll
    for (int i = 0; i < 2; ++i) {
      int s = i * 256 + t;
      int row = s >> 3, c = s & 7;
      int cs = c ^ (row & 7);
      gload_lds16(kbuf + qk_base + (size_t)(kb0 + row) * 64 + cs * 8, (char*)k_lds + s * 16);
      gload_lds16(vtb + qk_base + (size_t)row * 2048 + kb0 + cs * 8, (char*)vt_lds + s * 16);
    }
    __syncthreads();
    // S = Q K^T (16 rows x 64 cols per wave)
    f32x4 s4[4] = {};
#pragma unroll
    for (int ks = 0; ks < 2; ++ks) {
      bf16x8 a = ks ? aq1 : aq0;
#pragma unroll
      for (int ni = 0; ni < 4; ++ni) {
        int row = ni * 16 + c16;
        int ch = (r16 + ks * 4) ^ (row & 7);
        bf16x8 bk = *(const bf16x8*)&k_lds[row * 64 + ch * 8];
        s4[ni] = __builtin_amdgcn_mfma_f32_16x16x32_bf16(a, bk, s4[ni], 0, 0, 0);
      }
    }
    // + bias, online softmax
    float sv[4][4], pp[4][4];
#pragma unroll
    for (int r = 0; r < 4; ++r) {
      const unsigned short* bp = biasb + (size_t)(qrow_g + r) * 2048 + kb0 + c16;
#pragma unroll
      for (int ni = 0; ni < 4; ++ni) sv[ni][r] = s4[ni][r] + bf2f(bp[ni * 16]);
    }
#pragma unroll
    for (int r = 0; r < 4; ++r) {
      float tm = fmaxf(fmaxf(sv[0][r], sv[1][r]), fmaxf(sv[2][r], sv[3][r]));
      tm = fmaxf(tm, __shfl_xor(tm, 1));
      tm = fmaxf(tm, __shfl_xor(tm, 2));
      tm = fmaxf(tm, __shfl_xor(tm, 4));
      tm = fmaxf(tm, __shfl_xor(tm, 8));
      float mn = fmaxf(mrow[r], tm);
      float fr = __expf(mrow[r] - mn);
      float ts = 0.f;
#pragma unroll
      for (int ni = 0; ni < 4; ++ni) {
        float pv = __expf(sv[ni][r] - mn);
        pp[ni][r] = pv;
        ts += pv;
      }
      ts += __shfl_xor(ts, 1);
      ts += __shfl_xor(ts, 2);
      ts += __shfl_xor(ts, 4);
      ts += __shfl_xor(ts, 8);
      lrow[r] = lrow[r] * fr + ts;
      mrow[r] = mn;
#pragma unroll
      for (int nd = 0; nd < 4; ++nd) o[nd][r] *= fr;
    }
    // P -> LDS (swizzled, wave-private rows), then O += P V
#pragma unroll
    for (int ni = 0; ni < 4; ++ni)
#pragma unroll
      for (int r = 0; r < 4; ++r) {
        int rowl = w * 16 + r16 * 4 + r;
        int col = (ni * 16 + c16) ^ ((rowl & 7) << 3);
        p_lds[rowl * 64 + col] = f2bf(pp[ni][r]);
      }
#pragma unroll
    for (int ks = 0; ks < 2; ++ks) {
      int prow = w * 16 + c16;
      int ch = (r16 + ks * 4) ^ (prow & 7);
      bf16x8 ap = *(const bf16x8*)&p_lds[prow * 64 + ch * 8];
#pragma unroll
      for (int nd = 0; nd < 4; ++nd) {
        int drow = nd * 16 + c16;
        int chv = (r16 + ks * 4) ^ (drow & 7);
        bf16x8 bv = *(const bf16x8*)&vt_lds[drow * 64 + chv * 8];
        o[nd] = __builtin_amdgcn_mfma_f32_16x16x32_bf16(ap, bv, o[nd], 0, 0, 0);
      }
    }
    __syncthreads();
  }
  const int b = bh >> 4, h = bh & 15;
#pragma unroll
  for (int nd = 0; nd < 4; ++nd)
#pragma unroll
    for (int r = 0; r < 4; ++r) {
      int lq = qrow_g + r;
      int d = nd * 16 + c16;
      float val = o[nd][r] / lrow[r];
      oup[((size_t)b * 2048 + lq) * 1024 + h * 64 + d] = f2bf(val);
    }
}

extern "C" void kernel_launch(void* const* d_in, const int* in_sizes, int n_in,
                              void* d_out, int out_size, void* d_ws, size_t ws_size,
                              hipStream_t stream) {
  const float* x = (const float*)d_in[0];
  const float* attn_bias = (const float*)d_in[1];
  const float* W_qkv = (const float*)d_in[2];
  const float* q_bias = (const float*)d_in[3];
  const float* v_bias = (const float*)d_in[4];
  const float* scale_mul = (const float*)d_in[5];
  const float* W_proj = (const float*)d_in[6];
  const float* b_proj = (const float*)d_in[7];
  float* out = (float*)d_out;
  char* ws = (char*)d_ws;

  // workspace layout (bytes)
  unsigned short* x_bf = (unsigned short*)(ws + 0);           //  8 MB: 4096x1024
  unsigned short* wqkv_bf = (unsigned short*)(ws + 8388608);  //  6 MB: 3072x1024
  unsigned short* wproj_bf = (unsigned short*)(ws + 14680064);//  2 MB: 1024x1024
  unsigned short* bias_bf = (unsigned short*)(ws + 16777216); //  8 MB: 2048x2048
  unsigned short* q_pk = (unsigned short*)(ws + 25165824);    //  8 MB: (B,H,L,D)
  unsigned short* k_pk = (unsigned short*)(ws + 33554432);    //  8 MB: (B,H,L,D)
  unsigned short* vt_pk = (unsigned short*)(ws + 41943040);   //  8 MB: (B,H,D,L)
  unsigned short* oup_bf = (unsigned short*)(ws + 50331648);  //  8 MB: (B,L,C)
  unsigned short* pre_qkv = (unsigned short*)(ws + 58720256); // 24 MB: 4096x3072
  // total 80 MB

  cvt_bf16<<<2048, 256, 0, stream>>>(x, x_bf, 524288);
  cvt_bf16<<<1536, 256, 0, stream>>>(W_qkv, wqkv_bf, 393216);
  cvt_bf16<<<512, 256, 0, stream>>>(W_proj, wproj_bf, 131072);
  cvt_bf16<<<2048, 256, 0, stream>>>(attn_bias, bias_bf, 524288);

  gemm_nt<false><<<dim3(24, 32), 256, 0, stream>>>(x_bf, wqkv_bf, (void*)pre_qkv, nullptr,
                                                   4096, 3072, 1024);
  norm_pack<<<dim3(64, 48), 256, 0, stream>>>(pre_qkv, q_bias, v_bias, scale_mul,
                                              q_pk, k_pk, vt_pk);
  attn_fwd<<<dim3(32, 32), 256, 0, stream>>>(q_pk, k_pk, vt_pk, bias_bf, oup_bf);
  gemm_nt<true><<<dim3(8, 32), 256, 0, stream>>>(oup_bf, wproj_bf, (void*)out, b_proj,
                                                 4096, 1024, 1024);
}

// Round 2
// 163.601 us; speedup vs baseline: 1.2986x; 1.2986x over previous
//
#include <hip/hip_runtime.h>

typedef short bf16x8 __attribute__((ext_vector_type(8)));
typedef short bf16x4 __attribute__((ext_vector_type(4)));
typedef unsigned short u16x8 __attribute__((ext_vector_type(8)));
typedef float f32x4 __attribute__((ext_vector_type(4)));

__device__ __forceinline__ float bf2f(unsigned short u) {
  union { unsigned int i; float f; } v; v.i = ((unsigned int)u) << 16; return v.f;
}
__device__ __forceinline__ unsigned short f2bf(float f) {
  union { float fl; unsigned int i; } v; v.fl = f;
  unsigned int r = v.i + 0x7FFFu + ((v.i >> 16) & 1u);
  return (unsigned short)(r >> 16);
}
__device__ __forceinline__ unsigned int cvt_pk_bf16(float lo, float hi) {
  unsigned int d;
  asm("v_cvt_pk_bf16_f32 %0, %1, %2" : "=v"(d) : "v"(lo), "v"(hi));
  return d;
}
__device__ __forceinline__ void gload_lds16(const void* g, void* l) {
  __builtin_amdgcn_global_load_lds(
      (const __attribute__((address_space(1))) void*)g,
      (__attribute__((address_space(3))) void*)l, 16, 0, 0);
}

// ---------------- fp32 -> bf16 conversion (8 elems/thread) ----------------
__global__ __launch_bounds__(256) void cvt_bf16(const float* __restrict__ in,
                                                unsigned short* __restrict__ out, int n8) {
  int i = blockIdx.x * 256 + threadIdx.x;
  if (i >= n8) return;
  float4 a = ((const float4*)in)[2 * i];
  float4 b = ((const float4*)in)[2 * i + 1];
  u16x8 o;
  o[0] = f2bf(a.x); o[1] = f2bf(a.y); o[2] = f2bf(a.z); o[3] = f2bf(a.w);
  o[4] = f2bf(b.x); o[5] = f2bf(b.y); o[6] = f2bf(b.z); o[7] = f2bf(b.w);
  ((u16x8*)out)[i] = o;
}

// ---------------- GEMM NT: out[m][n] = sum_k A[m][k]*B[n][k] ----------------
template <bool F32OUT>
__global__ __launch_bounds__(256) void gemm_nt(const unsigned short* __restrict__ A,
                                               const unsigned short* __restrict__ B,
                                               void* __restrict__ Cout,
                                               const float* __restrict__ bias,
                                               int M, int N, int K) {
  __shared__ __align__(16) unsigned short a_lds[128 * 64];
  __shared__ __align__(16) unsigned short b_lds[128 * 64];
  const int t = threadIdx.x;
  const int lane = t & 63, w = t >> 6;
  const int wm = w >> 1, wn = w & 1;
  const int r16 = lane >> 4, c16 = lane & 15;
  const int m0 = blockIdx.y * 128, n0 = blockIdx.x * 128;
  f32x4 acc[4][4] = {};
  for (int k0 = 0; k0 < K; k0 += 64) {
#pragma unroll
    for (int i = 0; i < 4; ++i) {
      int s = i * 256 + t;
      int row = s >> 3, c = s & 7;
      int cs = c ^ (row & 7);
      gload_lds16(A + (size_t)(m0 + row) * K + k0 + cs * 8, (char*)a_lds + s * 16);
      gload_lds16(B + (size_t)(n0 + row) * K + k0 + cs * 8, (char*)b_lds + s * 16);
    }
    __syncthreads();
#pragma unroll
    for (int ks = 0; ks < 2; ++ks) {
      bf16x8 af[4], bfr[4];
#pragma unroll
      for (int mi = 0; mi < 4; ++mi) {
        int row = wm * 64 + mi * 16 + c16;
        int ch = (r16 + ks * 4) ^ (row & 7);
        af[mi] = *(const bf16x8*)&a_lds[row * 64 + ch * 8];
      }
#pragma unroll
      for (int ni = 0; ni < 4; ++ni) {
        int row = wn * 64 + ni * 16 + c16;
        int ch = (r16 + ks * 4) ^ (row & 7);
        bfr[ni] = *(const bf16x8*)&b_lds[row * 64 + ch * 8];
      }
#pragma unroll
      for (int mi = 0; mi < 4; ++mi)
#pragma unroll
        for (int ni = 0; ni < 4; ++ni)
          acc[mi][ni] = __builtin_amdgcn_mfma_f32_16x16x32_bf16(af[mi], bfr[ni], acc[mi][ni], 0, 0, 0);
    }
    __syncthreads();
  }
#pragma unroll
  for (int mi = 0; mi < 4; ++mi)
#pragma unroll
    for (int ni = 0; ni < 4; ++ni)
#pragma unroll
      for (int r = 0; r < 4; ++r) {
        int m = m0 + wm * 64 + mi * 16 + r16 * 4 + r;
        int n = n0 + wn * 64 + ni * 16 + c16;
        float v = acc[mi][ni][r];
        if constexpr (F32OUT) {
          ((float*)Cout)[(size_t)m * N + n] = v + bias[n];
        } else {
          ((unsigned short*)Cout)[(size_t)m * N + n] = f2bf(v);
        }
      }
}

// ---------------- normalize + bias + pack q,k,(v transposed) ----------------
__global__ __launch_bounds__(256) void norm_pack(const unsigned short* __restrict__ pre,
                                                 const float* __restrict__ q_bias,
                                                 const float* __restrict__ v_bias,
                                                 const float* __restrict__ scale_mul,
                                                 unsigned short* __restrict__ qo,
                                                 unsigned short* __restrict__ ko,
                                                 unsigned short* __restrict__ vto) {
  __shared__ float tl[64][65];
  const int t = threadIdx.x;
  const int li = t >> 2, dq = t & 3;
  const int tile = blockIdx.x;  // b*32 + lt
  const int sl = blockIdx.y;    // qkv*16 + h
  const int qkv = sl >> 4, h = sl & 15;
  const int b = tile >> 5, lt = tile & 31;
  const int l = lt * 64 + li;
  const int dbase = dq * 16;
  const unsigned short* src = pre + ((size_t)b * 2048 + l) * 3072 + qkv * 1024 + h * 64 + dbase;
  float v[16];
  bf16x8 x0 = *(const bf16x8*)src;
  bf16x8 x1 = *(const bf16x8*)(src + 8);
#pragma unroll
  for (int j = 0; j < 8; ++j) {
    v[j] = bf2f((unsigned short)x0[j]);
    v[8 + j] = bf2f((unsigned short)x1[j]);
  }
  if (qkv == 0) {
#pragma unroll
    for (int j = 0; j < 16; ++j) v[j] += q_bias[h * 64 + dbase + j];
  } else if (qkv == 2) {
#pragma unroll
    for (int j = 0; j < 16; ++j) v[j] += v_bias[h * 64 + dbase + j];
  }
  if (qkv < 2) {
    float ss = 0.f;
#pragma unroll
    for (int j = 0; j < 16; ++j) ss += v[j] * v[j];
    ss += __shfl_xor(ss, 1);
    ss += __shfl_xor(ss, 2);
    float inv = 1.0f / fmaxf(sqrtf(ss), 1e-12f);
    if (qkv == 0) inv *= __expf(fminf(scale_mul[h], 4.6051701859880914f));
    u16x8 o0, o1;
#pragma unroll
    for (int j = 0; j < 8; ++j) {
      o0[j] = f2bf(v[j] * inv);
      o1[j] = f2bf(v[8 + j] * inv);
    }
    unsigned short* dst = (qkv == 0 ? qo : ko) + ((size_t)(b * 16 + h) * 2048 + l) * 64 + dbase;
    *(u16x8*)dst = o0;
    *(u16x8*)(dst + 8) = o1;
  } else {
#pragma unroll
    for (int j = 0; j < 16; ++j) tl[li][dbase + j] = v[j];
    __syncthreads();
    const int d = li;
    const int lb = dq * 16;
    u16x8 o0, o1;
#pragma unroll
    for (int j = 0; j < 8; ++j) {
      o0[j] = f2bf(tl[lb + j][d]);
      o1[j] = f2bf(tl[lb + 8 + j][d]);
    }
    unsigned short* dst = vto + ((size_t)(b * 16 + h) * 64 + d) * 2048 + lt * 64 + lb;
    *(u16x8*)dst = o0;
    *(u16x8*)(dst + 8) = o1;
  }
}

// ---------------- flash attention, swapped-QK^T, fixed per-head max ----------------
// 64 q-rows/block, 4 waves x 16 rows. S^T fragments: lane (r16,c16) holds
// S[k = mi*16 + r16*4 + r][q = c16] -> softmax row is lane-local, no per-iter shfl.
__global__ __launch_bounds__(256) void attn_fwd(const unsigned short* __restrict__ qb,
                                                const unsigned short* __restrict__ kbuf,
                                                const unsigned short* __restrict__ vtb,
                                                const unsigned short* __restrict__ biasb,
                                                const float* __restrict__ scale_mul,
                                                unsigned short* __restrict__ oup) {
  __shared__ __align__(16) unsigned short k_lds[64 * 64];
  __shared__ __align__(16) unsigned short vt_lds[64 * 64];
  __shared__ __align__(16) unsigned short b_lds[64 * 64];
  __shared__ __align__(16) unsigned short p_lds[64 * 64];
  const int t = threadIdx.x;
  const int lane = t & 63, w = t >> 6;
  const int r16 = lane >> 4, c16 = lane & 15;
  const int q0 = blockIdx.x * 64;
  const int bh = blockIdx.y;
  const int h = bh & 15;
  const size_t qk_base = (size_t)bh * 2048 * 64;
  // Q fragments in registers (B-operand of swapped QK^T; same content as A-frag).
  bf16x8 aq0, aq1;
  {
    int row = q0 + w * 16 + c16;
    const unsigned short* qp = qb + qk_base + (size_t)row * 64 + r16 * 8;
    aq0 = *(const bf16x8*)qp;
    aq1 = *(const bf16x8*)(qp + 32);
  }
  const float M = __expf(fminf(scale_mul[h], 4.6051701859880914f));
  f32x4 o[4] = {};
  float lsum = 0.f;
  const int prow = w * 16 + c16;     // this lane's q-row (local)
  const int m7 = c16 & 7;            // swizzle mask for q-row-indexed tiles
  for (int kb0 = 0; kb0 < 2048; kb0 += 64) {
#pragma unroll
    for (int i = 0; i < 2; ++i) {
      int s = i * 256 + t;
      int row = s >> 3, c = s & 7;
      int cs = c ^ (row & 7);
      gload_lds16(kbuf + qk_base + (size_t)(kb0 + row) * 64 + cs * 8, (char*)k_lds + s * 16);
      gload_lds16(vtb + qk_base + (size_t)row * 2048 + kb0 + cs * 8, (char*)vt_lds + s * 16);
      gload_lds16(biasb + (size_t)(q0 + row) * 2048 + kb0 + cs * 8, (char*)b_lds + s * 16);
    }
    __syncthreads();
    // S^T = K Q^T : s4[mi] rows = k (mi*16 + r16*4 + r), col = q (c16)
    f32x4 s4[4] = {};
    __builtin_amdgcn_s_setprio(1);
#pragma unroll
    for (int ks = 0; ks < 2; ++ks) {
      bf16x8 a = ks ? aq1 : aq0;
#pragma unroll
      for (int mi = 0; mi < 4; ++mi) {
        int row = mi * 16 + c16;
        int ch = (r16 + ks * 4) ^ (row & 7);
        bf16x8 bk = *(const bf16x8*)&k_lds[row * 64 + ch * 8];
        s4[mi] = __builtin_amdgcn_mfma_f32_16x16x32_bf16(bk, a, s4[mi], 0, 0, 0);
      }
    }
    __builtin_amdgcn_s_setprio(0);
    // softmax (fixed max M, lane-local row): p = exp(S + bias - M)
    float p[4][4];
#pragma unroll
    for (int mi = 0; mi < 4; ++mi) {
      int ch = (2 * mi + (r16 >> 1)) ^ m7;
      bf16x4 b4 = *(const bf16x4*)&b_lds[prow * 64 + ch * 8 + 4 * (r16 & 1)];
#pragma unroll
      for (int r = 0; r < 4; ++r) {
        float tv = s4[mi][r] + bf2f((unsigned short)b4[r]);
        p[mi][r] = __expf(tv - M);
      }
    }
#pragma unroll
    for (int mi = 0; mi < 4; ++mi)
      lsum += (p[mi][0] + p[mi][1]) + (p[mi][2] + p[mi][3]);
    // pack P pairs (k-adjacent, lane-local) -> p_lds[q][k] swizzled
#pragma unroll
    for (int mi = 0; mi < 4; ++mi)
#pragma unroll
      for (int r2 = 0; r2 < 2; ++r2) {
        unsigned int pk = cvt_pk_bf16(p[mi][2 * r2], p[mi][2 * r2 + 1]);
        int ch = (2 * mi + (r16 >> 1)) ^ m7;
        ((unsigned int*)p_lds)[prow * 32 + ch * 4 + 2 * (r16 & 1) + r2] = pk;
      }
    // O += P V  (A = P[q=c16][k-chunk], B = V^T)
    __builtin_amdgcn_s_setprio(1);
#pragma unroll
    for (int ks = 0; ks < 2; ++ks) {
      int ch = (4 * ks + r16) ^ m7;
      bf16x8 ap = *(const bf16x8*)&p_lds[prow * 64 + ch * 8];
#pragma unroll
      for (int nd = 0; nd < 4; ++nd) {
        int drow = nd * 16 + c16;
        int chv = (r16 + ks * 4) ^ (drow & 7);
        bf16x8 bv = *(const bf16x8*)&vt_lds[drow * 64 + chv * 8];
        o[nd] = __builtin_amdgcn_mfma_f32_16x16x32_bf16(ap, bv, o[nd], 0, 0, 0);
      }
    }
    __builtin_amdgcn_s_setprio(0);
    __syncthreads();
  }
  // row-sum: reduce across the 4 r16 groups (same c16 class), once.
  lsum += __shfl_xor(lsum, 16);
  lsum += __shfl_xor(lsum, 32);
  const int b = bh >> 4;
  const int qrow_g = q0 + w * 16 + r16 * 4;
#pragma unroll
  for (int r = 0; r < 4; ++r) {
    float lr = __shfl(lsum, r16 * 4 + r);  // total for q-local = w*16 + r16*4 + r
    float inv = 1.0f / lr;
#pragma unroll
    for (int nd = 0; nd < 4; ++nd) {
      int lq = qrow_g + r;
      int d = nd * 16 + c16;
      oup[((size_t)b * 2048 + lq) * 1024 + h * 64 + d] = f2bf(o[nd][r] * inv);
    }
  }
}

extern "C" void kernel_launch(void* const* d_in, const int* in_sizes, int n_in,
                              void* d_out, int out_size, void* d_ws, size_t ws_size,
                              hipStream_t stream) {
  const float* x = (const float*)d_in[0];
  const float* attn_bias = (const float*)d_in[1];
  const float* W_qkv = (const float*)d_in[2];
  const float* q_bias = (const float*)d_in[3];
  const float* v_bias = (const float*)d_in[4];
  const float* scale_mul = (const float*)d_in[5];
  const float* W_proj = (const float*)d_in[6];
  const float* b_proj = (const float*)d_in[7];
  float* out = (float*)d_out;
  char* ws = (char*)d_ws;

  unsigned short* x_bf = (unsigned short*)(ws + 0);           //  8 MB
  unsigned short* wqkv_bf = (unsigned short*)(ws + 8388608);  //  6 MB
  unsigned short* wproj_bf = (unsigned short*)(ws + 14680064);//  2 MB
  unsigned short* bias_bf = (unsigned short*)(ws + 16777216); //  8 MB
  unsigned short* q_pk = (unsigned short*)(ws + 25165824);    //  8 MB
  unsigned short* k_pk = (unsigned short*)(ws + 33554432);    //  8 MB
  unsigned short* vt_pk = (unsigned short*)(ws + 41943040);   //  8 MB
  unsigned short* oup_bf = (unsigned short*)(ws + 50331648);  //  8 MB
  unsigned short* pre_qkv = (unsigned short*)(ws + 58720256); // 24 MB

  cvt_bf16<<<2048, 256, 0, stream>>>(x, x_bf, 524288);
  cvt_bf16<<<1536, 256, 0, stream>>>(W_qkv, wqkv_bf, 393216);
  cvt_bf16<<<512, 256, 0, stream>>>(W_proj, wproj_bf, 131072);
  cvt_bf16<<<2048, 256, 0, stream>>>(attn_bias, bias_bf, 524288);

  gemm_nt<false><<<dim3(24, 32), 256, 0, stream>>>(x_bf, wqkv_bf, (void*)pre_qkv, nullptr,
                                                   4096, 3072, 1024);
  norm_pack<<<dim3(64, 48), 256, 0, stream>>>(pre_qkv, q_bias, v_bias, scale_mul,
                                              q_pk, k_pk, vt_pk);
  attn_fwd<<<dim3(32, 32), 256, 0, stream>>>(q_pk, k_pk, vt_pk, bias_bf, scale_mul, oup_bf);
  gemm_nt<true><<<dim3(8, 32), 256, 0, stream>>>(oup_bf, wproj_bf, (void*)out, b_proj,
                                                 4096, 1024, 1024);
}